// Round 1
// baseline (133.944 us; speedup 1.0000x reference)
//
#include <hip/hip_runtime.h>
#include <math.h>

#define NLEV 44
#define IMG 178
#define NPTS (IMG*IMG)
#define HASH_SIZE 1024
#define PRIME 2654435761u

struct LevelParams {
    int res[NLEV];
    int offs[NLEV];
    unsigned long long dense_mask;
};

__global__ __launch_bounds__(256) void shacira_kernel(
    const float* __restrict__ x, const float* __restrict__ codebook,
    const float* __restrict__ w1, const float* __restrict__ w2,
    const float* __restrict__ w3, float* __restrict__ out,
    int total, LevelParams lp)
{
    const int b = blockIdx.y;
    const int n = blockIdx.x * blockDim.x + threadIdx.x;

    __shared__ float sW1[16 * NLEV];
    __shared__ float sW2[16 * 16];
    __shared__ float sW3[3 * 16];
    {
        const float* w1b = w1 + (size_t)b * 16 * NLEV;
        const float* w2b = w2 + (size_t)b * 16 * 16;
        const float* w3b = w3 + (size_t)b * 3 * 16;
        for (int i = threadIdx.x; i < 16 * NLEV; i += blockDim.x) sW1[i] = w1b[i];
        if (threadIdx.x < 256) sW2[threadIdx.x] = w2b[threadIdx.x];
        if (threadIdx.x < 48)  sW3[threadIdx.x] = w3b[threadIdx.x];
    }
    __syncthreads();

    if (n >= NPTS) return;

    const float2 xy = reinterpret_cast<const float2*>(x)[(size_t)b * NPTS + n];
    const float* cb = codebook + (size_t)b * total;

    float feats[NLEV];
#pragma unroll
    for (int l = 0; l < NLEV; ++l) {
        const int res = lp.res[l];
        const float rf = (float)res;
        const float sx = xy.x * rf;
        const float sy = xy.y * rf;
        const float bxf = floorf(sx);
        const float byf = floorf(sy);
        const float fx = sx - bxf;
        const float fy = sy - byf;
        int ix0 = (int)bxf, iy0 = (int)byf;
        const int ix1 = min(ix0 + 1, res), iy1 = min(iy0 + 1, res);
        ix0 = min(ix0, res); iy0 = min(iy0, res);
        int i00, i01, i10, i11;
        if ((lp.dense_mask >> l) & 1ull) {
            const int st = res + 1;
            i00 = iy0 * st + ix0;   // corner (dx=0,dy=0)
            i01 = iy1 * st + ix0;   // corner (dx=0,dy=1)
            i10 = iy0 * st + ix1;   // corner (dx=1,dy=0)
            i11 = iy1 * st + ix1;   // corner (dx=1,dy=1)
        } else {
            const unsigned px0 = (unsigned)ix0, px1 = (unsigned)ix1;
            const unsigned py0 = (unsigned)iy0 * PRIME, py1 = (unsigned)iy1 * PRIME;
            i00 = (int)((px0 ^ py0) & (unsigned)(HASH_SIZE - 1));
            i01 = (int)((px0 ^ py1) & (unsigned)(HASH_SIZE - 1));
            i10 = (int)((px1 ^ py0) & (unsigned)(HASH_SIZE - 1));
            i11 = (int)((px1 ^ py1) & (unsigned)(HASH_SIZE - 1));
        }
        const int off = lp.offs[l];
        const float v00 = cb[off + i00];
        const float v01 = cb[off + i01];
        const float v10 = cb[off + i10];
        const float v11 = cb[off + i11];
        const float w00 = (1.f - fx) * (1.f - fy);
        const float w01 = (1.f - fx) * fy;
        const float w10 = fx * (1.f - fy);
        const float w11 = fx * fy;
        feats[l] = v00 * w00 + v01 * w01 + v10 * w10 + v11 * w11;
    }

    float h1[16];
#pragma unroll
    for (int o = 0; o < 16; ++o) {
        float acc = 0.f;
#pragma unroll
        for (int l = 0; l < NLEV; ++l) acc = fmaf(feats[l], sW1[o * NLEV + l], acc);
        h1[o] = fmaxf(acc, 0.f);
    }
    float h2[16];
#pragma unroll
    for (int o = 0; o < 16; ++o) {
        float acc = 0.f;
#pragma unroll
        for (int k = 0; k < 16; ++k) acc = fmaf(h1[k], sW2[o * 16 + k], acc);
        h2[o] = fmaxf(acc, 0.f);
    }
    float rgb[3];
#pragma unroll
    for (int c = 0; c < 3; ++c) {
        float acc = 0.f;
#pragma unroll
        for (int k = 0; k < 16; ++k) acc = fmaf(h2[k], sW3[c * 16 + k], acc);
        rgb[c] = 1.f / (1.f + expf(-acc));
    }
    float* op = out + ((size_t)b * NPTS + n) * 3;
    op[0] = rgb[0];
    op[1] = rgb[1];
    op[2] = rgb[2];
}

extern "C" void kernel_launch(void* const* d_in, const int* in_sizes, int n_in,
                              void* d_out, int out_size, void* d_ws, size_t ws_size,
                              hipStream_t stream) {
    const float* x        = (const float*)d_in[0];
    const float* codebook = (const float*)d_in[1];
    const float* w1       = (const float*)d_in[2];
    const float* w2       = (const float*)d_in[3];
    const float* w3       = (const float*)d_in[4];
    float* out = (float*)d_out;

    const int B = in_sizes[0] / (NPTS * 2);

    // Host-side precompute of per-level geometry (matches numpy reference).
    LevelParams lp;
    unsigned long long mask = 0;
    int off = 0;
    for (int l = 0; l < NLEV; ++l) {
        const double r = 16.0 * pow(128.0 / 16.0, (double)l / (double)(NLEV - 1));
        const int res = (int)llrint(r);  // round-half-even matches np.round
        lp.res[l] = res;
        lp.offs[l] = off;
        int sz;
        if ((long long)(res + 1) * (res + 1) <= HASH_SIZE) {
            mask |= (1ull << l);
            sz = (res + 1) * (res + 1);
        } else {
            sz = HASH_SIZE;
        }
        off += sz;
    }
    lp.dense_mask = mask;
    const int total = off;

    dim3 block(256);
    dim3 grid((NPTS + 255) / 256, B);
    shacira_kernel<<<grid, block, 0, stream>>>(x, codebook, w1, w2, w3, out, total, lp);
}